// Round 2
// baseline (1078.060 us; speedup 1.0000x reference)
//
#include <hip/hip_runtime.h>
#include <hip/hip_bf16.h>
#include <math.h>

typedef __hip_bfloat16 bf16;

// ---------------- dtype-flexible accessors ----------------
__device__ __forceinline__ float loadf(const void* p, size_t i, bool f32m) {
    return f32m ? ((const float*)p)[i]
                : __bfloat162float(((const bf16*)p)[i]);
}
__device__ __forceinline__ void storef(void* p, size_t i, float v, bool f32m) {
    if (f32m) ((float*)p)[i] = v;
    else      ((bf16*)p)[i] = __float2bfloat16(v);
}
// row 0 = src, row 1 = dst; e64 => buffer is int64, read low word
__device__ __forceinline__ int ldidx(const int* w, size_t e, bool e64, size_t E, int row) {
    return e64 ? w[2 * (row * E + e)] : w[row * E + e];
}

// ---------------- dtype detection ----------------
// flags[0] = 1.0 if float inputs are f32, 0.0 if bf16
// flags[1] = 1.0 if edge_index is int64, 0.0 if int32
__global__ void k_detect(const void* x, const int* ei, float* flags) {
    if (blockIdx.x != 0 || threadIdx.x != 0) return;
    const unsigned short* hx = (const unsigned short*)x;
    int tame = 0;
    for (int i = 0; i < 64; ++i) {
        unsigned short u = hx[2 * i];
        int ex = (u >> 7) & 0xFF;          // bf16 exponent field
        if (ex >= 117 && ex <= 136) tame++; // |v| in ~[2^-10, 2^9]
    }
    // genuine bf16 N(0,1) data: nearly all even elements tame.
    // f32-underlying: even bf16s are mantissa halves -> ~8% tame.
    flags[0] = (tame >= 48) ? 0.0f : 1.0f;
    int nz = 0;
    for (int i = 0; i < 64; ++i) nz += (ei[2 * i + 1] != 0);
    flags[1] = (nz == 0) ? 1.0f : 0.0f;
}

// ---------------- degree / norm ----------------
__global__ void k_init_deg(float* __restrict__ deg, int n) {
    int i = blockIdx.x * 256 + threadIdx.x;
    if (i < n) deg[i] = 1.0f;   // self-loop
}

__global__ void k_accum_deg(const int* __restrict__ ei, const float* __restrict__ flags,
                            float* __restrict__ deg, int E) {
    bool e64 = flags[1] > 0.5f;
    int e = blockIdx.x * 256 + threadIdx.x;
    if (e < E) atomicAdd(&deg[ldidx(ei, e, e64, E, 1)], 1.0f);
}

__global__ void k_rsqrt(float* __restrict__ deg, int n) {
    int i = blockIdx.x * 256 + threadIdx.x;
    if (i < n) deg[i] = rsqrtf(deg[i]);
}

// ---------------- dense transform: out[N,64] = X[N,K] @ W[K,64] ----------------
// XWS: X is our own f32 workspace buffer (ignore flag). Otherwise X is a
// flag-typed input. W is always a flag-typed input.
template <int K, bool XWS>
__global__ __launch_bounds__(256) void k_gemm(const void* __restrict__ X,
                                              const void* __restrict__ W,
                                              const float* __restrict__ flags,
                                              float* __restrict__ out, int n) {
    __shared__ float wT[64 * (K + 1)];
    __shared__ float xs[4 * K];
    bool f32m = flags[0] > 0.5f;
    int tid = threadIdx.x;
    for (int i = tid; i < 64 * K; i += 256) {
        int k = i >> 6, c = i & 63;            // W layout [K][64]
        wT[c * (K + 1) + k] = loadf(W, i, f32m);
    }
    int r0 = blockIdx.x * 4;
    for (int i = tid; i < 4 * K; i += 256) {
        int row = i / K, k = i % K;
        int r = r0 + row;
        float v = 0.0f;
        if (r < n) {
            size_t idx = (size_t)r * K + k;
            v = XWS ? ((const float*)X)[idx] : loadf(X, idx, f32m);
        }
        xs[i] = v;
    }
    __syncthreads();
    int row = tid >> 6, c = tid & 63;
    int r = r0 + row;
    if (r >= n) return;
    const float* xp = &xs[row * K];
    const float* wp = &wT[c * (K + 1)];
    float acc = 0.0f;
#pragma unroll
    for (int k = 0; k < K; ++k) acc += xp[k] * wp[k];
    out[(size_t)r * 64 + c] = acc;
}

// ---------------- aggregation ----------------
__global__ void k_self_init(const float* __restrict__ t, const float* __restrict__ dinv,
                            float* __restrict__ out, int total) {
    int i = blockIdx.x * 256 + threadIdx.x;
    if (i < total) {
        int node = i >> 6;
        float d = dinv[node];
        out[i] = t[i] * d * d;
    }
}

// one wave (64 lanes = 64 feats) per edge
__global__ __launch_bounds__(256) void k_edge_agg(const float* __restrict__ t,
                                                  const float* __restrict__ dinv,
                                                  const int* __restrict__ ei,
                                                  const float* __restrict__ flags,
                                                  float* __restrict__ out, int E) {
    bool e64 = flags[1] > 0.5f;
    int gid = blockIdx.x * 256 + threadIdx.x;
    int e = gid >> 6;
    int c = gid & 63;
    if (e >= E) return;
    int s = ldidx(ei, e, e64, E, 0);
    int d = ldidx(ei, e, e64, E, 1);
    float w = dinv[s] * dinv[d];
    float v = t[(size_t)s * 64 + c] * w;
    atomicAdd(&out[(size_t)d * 64 + c], v);
}

__global__ void k_bias_relu(float* __restrict__ h, const void* __restrict__ b,
                            const float* __restrict__ flags, int total) {
    bool f32m = flags[0] > 0.5f;
    int i = blockIdx.x * 256 + threadIdx.x;
    if (i < total) {
        float v = h[i] + loadf(b, i & 63, f32m);
        h[i] = fmaxf(v, 0.0f);
    }
}

__global__ void k_bias_emb(float* __restrict__ h, const void* __restrict__ b,
                           const float* __restrict__ flags,
                           void* __restrict__ out, size_t emb_base, int total) {
    bool f32m = flags[0] > 0.5f;
    int i = blockIdx.x * 256 + threadIdx.x;
    if (i < total) {
        float v = h[i] + loadf(b, i & 63, f32m);
        h[i] = v;
        storef(out, emb_base + i, v, f32m);
    }
}

// ---------------- classifier + softmax + argmax: one wave per node ----------------
__global__ __launch_bounds__(256) void k_classifier(const float* __restrict__ emb,
                                                    const void* __restrict__ Wc,
                                                    const void* __restrict__ bc,
                                                    const float* __restrict__ flags,
                                                    void* __restrict__ out,
                                                    size_t soft_base, size_t hard_base,
                                                    int n) {
    __shared__ float wc[40 * 65];   // wc[c*65 + k], Wc layout [64][40]
    __shared__ float bcs[40];
    __shared__ float ebuf[4][64];
    bool f32m = flags[0] > 0.5f;
    int tid = threadIdx.x;
    for (int i = tid; i < 64 * 40; i += 256) {
        int k = i / 40, c = i % 40;
        wc[c * 65 + k] = loadf(Wc, i, f32m);
    }
    if (tid < 40) bcs[tid] = loadf(bc, tid, f32m);
    int w = tid >> 6, lane = tid & 63;
    int node = blockIdx.x * 4 + w;
    ebuf[w][lane] = (node < n) ? emb[(size_t)node * 64 + lane] : 0.0f;
    __syncthreads();
    if (node >= n) return;

    int c = lane;
    float acc = -INFINITY;
    if (c < 40) {
        acc = bcs[c];
        const float* wp = &wc[c * 65];
#pragma unroll
        for (int k = 0; k < 64; ++k) acc += ebuf[w][k] * wp[k];
        storef(out, (size_t)node * 40 + c, acc, f32m);  // logits at base 0
    }
    float m = acc;
#pragma unroll
    for (int off = 32; off > 0; off >>= 1) m = fmaxf(m, __shfl_xor(m, off, 64));
    float ex = (c < 40) ? expf(acc - m) : 0.0f;
    float s = ex;
#pragma unroll
    for (int off = 32; off > 0; off >>= 1) s += __shfl_xor(s, off, 64);
    if (c < 40) storef(out, soft_base + (size_t)node * 40 + c, ex / s, f32m);
    float bv = acc;
    int bi = (c < 40) ? c : 1000;
#pragma unroll
    for (int off = 32; off > 0; off >>= 1) {
        float ov = __shfl_xor(bv, off, 64);
        int oi = __shfl_xor(bi, off, 64);
        if (ov > bv || (ov == bv && oi < bi)) { bv = ov; bi = oi; }
    }
    if (lane == 0) storef(out, hard_base + node, (float)bi, f32m);
}

extern "C" void kernel_launch(void* const* d_in, const int* in_sizes, int n_in,
                              void* d_out, int out_size, void* d_ws, size_t ws_size,
                              hipStream_t stream) {
    const void* x  = d_in[0];
    const int*  ei = (const int*)d_in[1];
    const void* W1 = d_in[2];
    const void* b1 = d_in[3];
    const void* W2 = d_in[4];
    const void* b2 = d_in[5];
    const void* Wc = d_in[6];
    const void* bc = d_in[7];

    const int n = in_sizes[0] / 128;   // 100000
    const int E = in_sizes[1] / 2;     // 1200000

    float* ws    = (float*)d_ws;
    float* flags = ws;                                       // 256 floats
    float* dinv  = ws + 256;                                 // n floats (padded)
    float* A     = dinv + (((size_t)n + 255) / 256) * 256;   // n*64 floats
    float* B     = A + (size_t)n * 64;                       // n*64 floats

    // output element offsets (return order: logits, embedding, soft, hard)
    const size_t emb_base  = (size_t)n * 40;
    const size_t soft_base = (size_t)n * 104;
    const size_t hard_base = (size_t)n * 144;

    const int total = n * 64;
    const int gN  = (n + 255) / 256;
    const int gE  = (E + 255) / 256;
    const int gT  = (total + 255) / 256;
    const int gEW = (E + 3) / 4;       // one wave per edge, 4 waves/block
    const int gNW = (n + 3) / 4;       // one wave per node / 4 rows per block

    k_detect<<<1, 64, 0, stream>>>(x, ei, flags);

    // degrees / norms
    k_init_deg<<<gN, 256, 0, stream>>>(dinv, n);
    k_accum_deg<<<gE, 256, 0, stream>>>(ei, flags, dinv, E);
    k_rsqrt<<<gN, 256, 0, stream>>>(dinv, n);

    // conv1: t1 = x @ W1 ; aggregate ; +b1 ; relu
    k_gemm<128, false><<<gNW, 256, 0, stream>>>(x, W1, flags, A, n);
    k_self_init<<<gT, 256, 0, stream>>>(A, dinv, B, total);
    k_edge_agg<<<gEW, 256, 0, stream>>>(A, dinv, ei, flags, B, E);
    k_bias_relu<<<gT, 256, 0, stream>>>(B, b1, flags, total);

    // conv2: t2 = h1 @ W2 ; aggregate ; +b2 -> embedding
    k_gemm<64, true><<<gNW, 256, 0, stream>>>(B, W2, flags, A, n);
    k_self_init<<<gT, 256, 0, stream>>>(A, dinv, B, total);
    k_edge_agg<<<gEW, 256, 0, stream>>>(A, dinv, ei, flags, B, E);
    k_bias_emb<<<gT, 256, 0, stream>>>(B, b2, flags, d_out, emb_base, total);

    // classifier + softmax + argmax
    k_classifier<<<gNW, 256, 0, stream>>>(B, Wc, bc, flags, d_out,
                                          soft_base, hard_base, n);
}

// Round 4
// 804.699 us; speedup vs baseline: 1.3397x; 1.3397x over previous
//
#include <hip/hip_runtime.h>
#include <hip/hip_bf16.h>
#include <math.h>

typedef __hip_bfloat16 bf16;

// ---------------- dtype-flexible accessors ----------------
__device__ __forceinline__ float loadf(const void* p, size_t i, bool f32m) {
    return f32m ? ((const float*)p)[i]
                : __bfloat162float(((const bf16*)p)[i]);
}
__device__ __forceinline__ void storef(void* p, size_t i, float v, bool f32m) {
    if (f32m) ((float*)p)[i] = v;
    else      ((bf16*)p)[i] = __float2bfloat16(v);
}
// row 0 = src, row 1 = dst; e64 => buffer is int64, read low word
__device__ __forceinline__ int ldidx(const int* w, size_t e, bool e64, size_t E, int row) {
    return e64 ? w[2 * (row * E + e)] : w[row * E + e];
}

// ---------------- dtype detection ----------------
// flags[0] = 1.0 if float inputs are f32 (evidence: this is the live path)
// flags[1] = 1.0 if edge_index is int64
__global__ void k_detect(const void* x, const int* ei, float* flags) {
    if (blockIdx.x != 0 || threadIdx.x != 0) return;
    const unsigned short* hx = (const unsigned short*)x;
    int tame = 0;
    for (int i = 0; i < 64; ++i) {
        unsigned short u = hx[2 * i];
        int ex = (u >> 7) & 0xFF;
        if (ex >= 117 && ex <= 136) tame++;
    }
    flags[0] = (tame >= 48) ? 0.0f : 1.0f;
    int nz = 0;
    for (int i = 0; i < 64; ++i) nz += (ei[2 * i + 1] != 0);
    flags[1] = (nz == 0) ? 1.0f : 0.0f;
}

// ---------------- CSR build ----------------
__global__ void k_zero(int* __restrict__ cnt, int n) {
    int i = blockIdx.x * 256 + threadIdx.x;
    if (i < n) cnt[i] = 0;
}

__global__ void k_hist(const int* __restrict__ ei, const float* __restrict__ flags,
                       int* __restrict__ cnt, int E) {
    bool e64 = flags[1] > 0.5f;
    int e = blockIdx.x * 256 + threadIdx.x;
    if (e < E) atomicAdd(&cnt[ldidx(ei, e, e64, E, 1)], 1);
}

// 1024 elements per block, 256 threads x 4
__global__ __launch_bounds__(256) void k_block_sums(const int* __restrict__ cnt,
                                                    int* __restrict__ bsum, int n) {
    __shared__ int red[256];
    int tid = threadIdx.x;
    int base = blockIdx.x * 1024 + tid * 4;
    int s = 0;
#pragma unroll
    for (int j = 0; j < 4; ++j) { int i = base + j; if (i < n) s += cnt[i]; }
    red[tid] = s;
    __syncthreads();
    for (int off = 128; off > 0; off >>= 1) {
        if (tid < off) red[tid] += red[tid + off];
        __syncthreads();
    }
    if (tid == 0) bsum[blockIdx.x] = red[0];
}

// single block: exclusive scan of block sums (nb <= 256); also rowptr[n] = E
__global__ __launch_bounds__(256) void k_scan_bsum(int* __restrict__ bsum, int nb,
                                                   int* __restrict__ rowptr, int n, int E) {
    __shared__ int sh[256];
    int tid = threadIdx.x;
    int v = (tid < nb) ? bsum[tid] : 0;
    sh[tid] = v;
    __syncthreads();
    for (int off = 1; off < 256; off <<= 1) {
        int t = (tid >= off) ? sh[tid - off] : 0;
        __syncthreads();
        sh[tid] += t;
        __syncthreads();
    }
    if (tid < nb) bsum[tid] = sh[tid] - v;   // exclusive
    if (tid == 0) rowptr[n] = E;
}

// per-block rescan -> rowptr (exclusive), cursor copy, dinv = rsqrt(indeg+1)
__global__ __launch_bounds__(256) void k_scan_final(const int* __restrict__ cnt_in,
                                                    const int* __restrict__ bsum,
                                                    int* __restrict__ rowptr,
                                                    int* __restrict__ cursor,
                                                    float* __restrict__ dinv, int n) {
    __shared__ int sh[256];
    int tid = threadIdx.x;
    int base = blockIdx.x * 1024 + tid * 4;
    int c[4];
    int s = 0;
#pragma unroll
    for (int j = 0; j < 4; ++j) {
        int i = base + j;
        c[j] = (i < n) ? cnt_in[i] : 0;
        s += c[j];
    }
    sh[tid] = s;
    __syncthreads();
    for (int off = 1; off < 256; off <<= 1) {
        int t = (tid >= off) ? sh[tid - off] : 0;
        __syncthreads();
        sh[tid] += t;
        __syncthreads();
    }
    int run = bsum[blockIdx.x] + sh[tid] - s;
#pragma unroll
    for (int j = 0; j < 4; ++j) {
        int i = base + j;
        if (i < n) {
            rowptr[i] = run;
            cursor[i] = run;
            dinv[i] = rsqrtf((float)(c[j] + 1));
            run += c[j];
        }
    }
}

__global__ void k_scatter(const int* __restrict__ ei, const float* __restrict__ flags,
                          int* __restrict__ cursor, int* __restrict__ srcs, int E) {
    bool e64 = flags[1] > 0.5f;
    int e = blockIdx.x * 256 + threadIdx.x;
    if (e < E) {
        int s = ldidx(ei, e, e64, E, 0);
        int d = ldidx(ei, e, e64, E, 1);
        int pos = atomicAdd(&cursor[d], 1);
        srcs[pos] = s;
    }
}

// ---------------- dense transform: out[N,64](f32) = X[N,K] @ W[K,64] ----------------
// 32 rows/block, 4 waves, 8 rows/wave. W staged in LDS [K][64] f32.
// X pointer picked device-side by flag: Xa if f32m else Xb. XF32: X elements
// are f32 regardless of flag (workspace/d_out buffers).
template <int K, bool XF32>
__global__ __launch_bounds__(256) void k_gemm2(const void* __restrict__ Xa,
                                               const void* __restrict__ Xb,
                                               const void* __restrict__ W,
                                               const float* __restrict__ flags,
                                               float* __restrict__ out, int n) {
    __shared__ float wl[K * 64];
    bool f32m = flags[0] > 0.5f;
    const void* X = f32m ? Xa : Xb;
    bool xf32 = XF32 || f32m;
    int tid = threadIdx.x;
    for (int i = tid; i < K * 64; i += 256) wl[i] = loadf(W, i, f32m);
    __syncthreads();
    int lane = tid & 63, wv = tid >> 6;
    int r0 = (blockIdx.x * 4 + wv) * 8;
    float acc[8] = {0, 0, 0, 0, 0, 0, 0, 0};
    for (int kc = 0; kc < K; kc += 8) {
        float xv[8][8];
#pragma unroll
        for (int r = 0; r < 8; ++r) {
            int row = __builtin_amdgcn_readfirstlane(r0 + r);
            if (row < n) {
                size_t base = (size_t)row * K + kc;
                if (xf32) {
                    const float* p = (const float*)X + base;
#pragma unroll
                    for (int j = 0; j < 8; ++j) xv[r][j] = p[j];
                } else {
                    const bf16* p = (const bf16*)X + base;
#pragma unroll
                    for (int j = 0; j < 8; ++j) xv[r][j] = __bfloat162float(p[j]);
                }
            } else {
#pragma unroll
                for (int j = 0; j < 8; ++j) xv[r][j] = 0.0f;
            }
        }
#pragma unroll
        for (int j = 0; j < 8; ++j) {
            float w = wl[(kc + j) * 64 + lane];
#pragma unroll
            for (int r = 0; r < 8; ++r) acc[r] += xv[r][j] * w;
        }
    }
#pragma unroll
    for (int r = 0; r < 8; ++r) {
        int row = r0 + r;
        if (row < n) out[(size_t)row * 64 + lane] = acc[r];
    }
}

// ---------------- fused aggregation: one wave per node ----------------
// acc = t[v]*dv^2 + sum_e t[src]*dinv[src]*dv + bias.
// EP=0 (conv1+relu): dst = f32m ? d_out emb region (scratch) : B_ws.
// EP=1 (conv2):      dst = f32m ? d_out emb region (final)   : B_ws + bf16 emb out.
template <int EP>
__global__ __launch_bounds__(256) void k_agg(const float* __restrict__ t,
                                             const float* __restrict__ dinv,
                                             const int* __restrict__ rowptr,
                                             const int* __restrict__ srcs,
                                             const void* __restrict__ bias,
                                             const float* __restrict__ flags,
                                             void* __restrict__ d_out, size_t emb_base,
                                             float* __restrict__ B_ws, int n) {
    bool f32m = flags[0] > 0.5f;
    int wid = (blockIdx.x * 256 + threadIdx.x) >> 6;
    int lane = threadIdx.x & 63;
    if (wid >= n) return;
    float dv = dinv[wid];
    float acc = t[(size_t)wid * 64 + lane] * dv * dv;
    int e0 = rowptr[wid], e1 = rowptr[wid + 1];
    for (int base = e0; base < e1; base += 64) {
        int m = e1 - base; if (m > 64) m = 64;
        int idx = base + lane;
        int s_l = (idx < e1) ? srcs[idx] : 0;
        float dv_l = (idx < e1) ? dinv[s_l] : 0.0f;
        for (int j = 0; j < m; ++j) {
            int s = __shfl(s_l, j, 64);
            float w = __shfl(dv_l, j, 64) * dv;
            acc += t[(size_t)s * 64 + lane] * w;
        }
    }
    acc += loadf(bias, lane, f32m);
    size_t oi = (size_t)wid * 64 + lane;
    if (EP == 0) acc = fmaxf(acc, 0.0f);
    if (f32m) {
        ((float*)d_out)[emb_base + oi] = acc;
    } else {
        B_ws[oi] = acc;
        if (EP == 1) ((bf16*)d_out)[emb_base + oi] = __float2bfloat16(acc);
    }
}

// ---------------- classifier + softmax + argmax: one wave per node ----------------
__global__ __launch_bounds__(256) void k_classifier(const float* __restrict__ flags,
                                                    const void* __restrict__ Wc,
                                                    const void* __restrict__ bc,
                                                    void* __restrict__ out,
                                                    size_t emb_base, size_t soft_base,
                                                    size_t hard_base,
                                                    const float* __restrict__ B_ws,
                                                    int n) {
    __shared__ float wc[40 * 65];
    __shared__ float bcs[40];
    __shared__ float ebuf[4][64];
    bool f32m = flags[0] > 0.5f;
    const float* emb = f32m ? ((const float*)out + emb_base) : B_ws;
    int tid = threadIdx.x;
    for (int i = tid; i < 64 * 40; i += 256) {
        int k = i / 40, c = i % 40;
        wc[c * 65 + k] = loadf(Wc, i, f32m);
    }
    if (tid < 40) bcs[tid] = loadf(bc, tid, f32m);
    int w = tid >> 6, lane = tid & 63;
    int node = blockIdx.x * 4 + w;
    ebuf[w][lane] = (node < n) ? emb[(size_t)node * 64 + lane] : 0.0f;
    __syncthreads();
    if (node >= n) return;

    int c = lane;
    float acc = -INFINITY;
    if (c < 40) {
        acc = bcs[c];
        const float* wp = &wc[c * 65];
#pragma unroll
        for (int k = 0; k < 64; ++k) acc += ebuf[w][k] * wp[k];
        storef(out, (size_t)node * 40 + c, acc, f32m);
    }
    float m = acc;
#pragma unroll
    for (int off = 32; off > 0; off >>= 1) m = fmaxf(m, __shfl_xor(m, off, 64));
    float ex = (c < 40) ? expf(acc - m) : 0.0f;
    float s = ex;
#pragma unroll
    for (int off = 32; off > 0; off >>= 1) s += __shfl_xor(s, off, 64);
    if (c < 40) storef(out, soft_base + (size_t)node * 40 + c, ex / s, f32m);
    float bv = acc;
    int bi = (c < 40) ? c : 1000;
#pragma unroll
    for (int off = 32; off > 0; off >>= 1) {
        float ov = __shfl_xor(bv, off, 64);
        int oi = __shfl_xor(bi, off, 64);
        if (ov > bv || (ov == bv && oi < bi)) { bv = ov; bi = oi; }
    }
    if (lane == 0) storef(out, hard_base + node, (float)bi, f32m);
}

extern "C" void kernel_launch(void* const* d_in, const int* in_sizes, int n_in,
                              void* d_out, int out_size, void* d_ws, size_t ws_size,
                              hipStream_t stream) {
    const void* x  = d_in[0];
    const int*  ei = (const int*)d_in[1];
    const void* W1 = d_in[2];
    const void* b1 = d_in[3];
    const void* W2 = d_in[4];
    const void* b2 = d_in[5];
    const void* Wc = d_in[6];
    const void* bc = d_in[7];

    const int n = in_sizes[0] / 128;   // 100000
    const int E = in_sizes[1] / 2;     // 1200000

    // ws layout (4-byte words). Total live use ~31.6 MB (B_ws only if !f32m).
    float* ws    = (float*)d_ws;
    const size_t npad = (((size_t)n + 1023) / 1024) * 1024;
    const size_t Epad = (((size_t)E + 255) / 256) * 256;
    float* flags = ws;                          // [0..256); bsum at [128..128+nb)
    int*   bsum  = (int*)(ws + 128);
    int*   cnt   = (int*)(ws + 256);            // npad (becomes cursor)
    int*   rowptr= cnt + npad;                  // npad (n+1 used)
    float* dinv  = (float*)(rowptr + npad);     // npad
    int*   srcs  = (int*)(dinv + npad);         // Epad
    float* A     = (float*)(srcs + Epad);       // n*64 f32 (gemm outputs)
    float* B_ws  = A + (size_t)n * 64;          // n*64 f32 (only touched if !f32m)

    // output element offsets (f32 elements in the live path)
    const size_t emb_base  = (size_t)n * 40;
    const size_t soft_base = (size_t)n * 104;
    const size_t hard_base = (size_t)n * 144;
    // h1 scratch lives in the d_out embedding region (n*64 f32) when f32m:
    float* h1_f32m = (float*)d_out + emb_base;

    const int gN  = (n + 255) / 256;
    const int gE  = (E + 255) / 256;
    const int nb  = (n + 1023) / 1024;          // 98 <= 128
    const int gG  = (n + 31) / 32;              // 32 rows per gemm block
    const int gW  = (n + 3) / 4;                // one wave per node

    k_detect<<<1, 64, 0, stream>>>(x, ei, flags);

    // CSR build (+ degrees)
    k_zero<<<gN, 256, 0, stream>>>(cnt, n);
    k_hist<<<gE, 256, 0, stream>>>(ei, flags, cnt, E);
    k_block_sums<<<nb, 256, 0, stream>>>(cnt, bsum, n);
    k_scan_bsum<<<1, 256, 0, stream>>>(bsum, nb, rowptr, n, E);
    k_scan_final<<<nb, 256, 0, stream>>>(cnt, bsum, rowptr, cnt, dinv, n);
    k_scatter<<<gE, 256, 0, stream>>>(ei, flags, cnt, srcs, E);

    // conv1: A = x @ W1 ; fused agg + b1 + relu -> h1 (emb region scratch / B_ws)
    k_gemm2<128, false><<<gG, 256, 0, stream>>>(x, x, W1, flags, A, n);
    k_agg<0><<<gW, 256, 0, stream>>>(A, dinv, rowptr, srcs, b1, flags,
                                     d_out, emb_base, B_ws, n);

    // conv2: A = h1 @ W2 ; fused agg + b2 -> final embedding
    k_gemm2<64, true><<<gG, 256, 0, stream>>>(h1_f32m, B_ws, W2, flags, A, n);
    k_agg<1><<<gW, 256, 0, stream>>>(A, dinv, rowptr, srcs, b2, flags,
                                     d_out, emb_base, B_ws, n);

    // classifier + softmax + argmax
    k_classifier<<<gW, 256, 0, stream>>>(flags, Wc, bc, d_out,
                                         emb_base, soft_base, hard_base, B_ws, n);
}

// Round 5
// 495.711 us; speedup vs baseline: 2.1748x; 1.6233x over previous
//
#include <hip/hip_runtime.h>
#include <hip/hip_bf16.h>
#include <math.h>

typedef __hip_bfloat16 bf16;

// ---------------- dtype-flexible accessors ----------------
__device__ __forceinline__ float loadf(const void* p, size_t i, bool f32m) {
    return f32m ? ((const float*)p)[i]
                : __bfloat162float(((const bf16*)p)[i]);
}
__device__ __forceinline__ void storef(void* p, size_t i, float v, bool f32m) {
    if (f32m) ((float*)p)[i] = v;
    else      ((bf16*)p)[i] = __float2bfloat16(v);
}
__device__ __forceinline__ int ldidx(const int* w, size_t e, bool e64, size_t E, int row) {
    return e64 ? w[2 * (row * E + e)] : w[row * E + e];
}

// ---------------- dtype detection ----------------
__global__ void k_detect(const void* x, const int* ei, float* flags) {
    if (blockIdx.x != 0 || threadIdx.x != 0) return;
    const unsigned short* hx = (const unsigned short*)x;
    int tame = 0;
    for (int i = 0; i < 64; ++i) {
        unsigned short u = hx[2 * i];
        int ex = (u >> 7) & 0xFF;
        if (ex >= 117 && ex <= 136) tame++;
    }
    flags[0] = (tame >= 48) ? 0.0f : 1.0f;   // 1 => f32 inputs (live path)
    int nz = 0;
    for (int i = 0; i < 64; ++i) nz += (ei[2 * i + 1] != 0);
    flags[1] = (nz == 0) ? 1.0f : 0.0f;      // 1 => int64 edge_index
}

// ---------------- CSR build ----------------
__global__ void k_zero(int* __restrict__ cnt, int n) {
    int i = blockIdx.x * 256 + threadIdx.x;
    if (i < n) cnt[i] = 0;
}

__global__ void k_hist(const int* __restrict__ ei, const float* __restrict__ flags,
                       int* __restrict__ cnt, int E) {
    bool e64 = flags[1] > 0.5f;
    int e = blockIdx.x * 256 + threadIdx.x;
    if (e < E) atomicAdd(&cnt[ldidx(ei, e, e64, E, 1)], 1);
}

__global__ __launch_bounds__(256) void k_block_sums(const int* __restrict__ cnt,
                                                    int* __restrict__ bsum, int n) {
    __shared__ int red[256];
    int tid = threadIdx.x;
    int base = blockIdx.x * 1024 + tid * 4;
    int s = 0;
#pragma unroll
    for (int j = 0; j < 4; ++j) { int i = base + j; if (i < n) s += cnt[i]; }
    red[tid] = s;
    __syncthreads();
    for (int off = 128; off > 0; off >>= 1) {
        if (tid < off) red[tid] += red[tid + off];
        __syncthreads();
    }
    if (tid == 0) bsum[blockIdx.x] = red[0];
}

__global__ __launch_bounds__(256) void k_scan_bsum(int* __restrict__ bsum, int nb,
                                                   int* __restrict__ rowptr, int n, int E) {
    __shared__ int sh[256];
    int tid = threadIdx.x;
    int v = (tid < nb) ? bsum[tid] : 0;
    sh[tid] = v;
    __syncthreads();
    for (int off = 1; off < 256; off <<= 1) {
        int t = (tid >= off) ? sh[tid - off] : 0;
        __syncthreads();
        sh[tid] += t;
        __syncthreads();
    }
    if (tid < nb) bsum[tid] = sh[tid] - v;   // exclusive
    if (tid == 0) rowptr[n] = E;
}

__global__ __launch_bounds__(256) void k_scan_final(const int* __restrict__ cnt_in,
                                                    const int* __restrict__ bsum,
                                                    int* __restrict__ rowptr,
                                                    int* __restrict__ cursor,
                                                    float* __restrict__ dinv, int n) {
    __shared__ int sh[256];
    int tid = threadIdx.x;
    int base = blockIdx.x * 1024 + tid * 4;
    int c[4];
    int s = 0;
#pragma unroll
    for (int j = 0; j < 4; ++j) {
        int i = base + j;
        c[j] = (i < n) ? cnt_in[i] : 0;
        s += c[j];
    }
    sh[tid] = s;
    __syncthreads();
    for (int off = 1; off < 256; off <<= 1) {
        int t = (tid >= off) ? sh[tid - off] : 0;
        __syncthreads();
        sh[tid] += t;
        __syncthreads();
    }
    int run = bsum[blockIdx.x] + sh[tid] - s;
#pragma unroll
    for (int j = 0; j < 4; ++j) {
        int i = base + j;
        if (i < n) {
            rowptr[i] = run;
            cursor[i] = run;
            dinv[i] = rsqrtf((float)(c[j] + 1));
            run += c[j];
        }
    }
}

__global__ void k_scatter(const int* __restrict__ ei, const float* __restrict__ flags,
                          int* __restrict__ cursor, int* __restrict__ srcs, int E) {
    bool e64 = flags[1] > 0.5f;
    int e = blockIdx.x * 256 + threadIdx.x;
    if (e < E) {
        int s = ldidx(ei, e, e64, E, 0);
        int d = ldidx(ei, e, e64, E, 1);
        int pos = atomicAdd(&cursor[d], 1);
        srcs[pos] = s;
    }
}

// ---------------- dense transform: out[N,64](f32) = X[N,K] @ W[K,64] ----------------
// 64 rows/block, X tile + W fully in LDS, 4x4 register tile per thread.
// xs stride K+4 (rows -> distinct banks for b128); wl stride 68 (2-way only).
template <int K, bool XF32>
__global__ __launch_bounds__(256) void k_gemm3(const void* __restrict__ Xa,
                                               const void* __restrict__ Xb,
                                               const void* __restrict__ W,
                                               const float* __restrict__ flags,
                                               float* __restrict__ out, int n) {
    __shared__ float xs[64 * (K + 4)];
    __shared__ float wl[K * 68];
    bool f32m = flags[0] > 0.5f;
    const void* X = f32m ? Xa : Xb;
    bool xf32 = XF32 || f32m;
    int tid = threadIdx.x;
    int r0 = blockIdx.x * 64;

    // stage W: [K][64] -> wl[k*68+c]
    if (f32m) {
        for (int i = tid * 4; i < K * 64; i += 1024) {
            int k = i >> 6, c = i & 63;
            float4 v = *(const float4*)((const float*)W + i);
            *(float4*)&wl[k * 68 + c] = v;
        }
    } else {
        for (int i = tid; i < K * 64; i += 256) {
            int k = i >> 6, c = i & 63;
            wl[k * 68 + c] = __bfloat162float(((const bf16*)W)[i]);
        }
    }
    // stage X tile: rows r0..r0+63 -> xs[row*(K+4)+k]
    if (xf32) {
        for (int i = tid * 4; i < 64 * K; i += 1024) {
            int row = i / K, k = i % K;
            float4 v = {0, 0, 0, 0};
            if (r0 + row < n) v = *(const float4*)((const float*)X + (size_t)(r0 + row) * K + k);
            *(float4*)&xs[row * (K + 4) + k] = v;
        }
    } else {
        for (int i = tid * 4; i < 64 * K; i += 1024) {
            int row = i / K, k = i % K;
            float4 v = {0, 0, 0, 0};
            if (r0 + row < n) {
                const bf16* p = (const bf16*)X + (size_t)(r0 + row) * K + k;
                v.x = __bfloat162float(p[0]); v.y = __bfloat162float(p[1]);
                v.z = __bfloat162float(p[2]); v.w = __bfloat162float(p[3]);
            }
            *(float4*)&xs[row * (K + 4) + k] = v;
        }
    }
    __syncthreads();

    int lane = tid & 63, wv = tid >> 6;
    int rg = lane >> 4, cg = lane & 15;          // 4 row-groups x 16 col-groups
    int rbase = wv * 16 + rg * 4;                // local row of first of 4
    int cbase = cg * 4;

    float acc[4][4];
#pragma unroll
    for (int r = 0; r < 4; ++r)
#pragma unroll
        for (int c = 0; c < 4; ++c) acc[r][c] = 0.0f;

#pragma unroll 2
    for (int k = 0; k < K; k += 4) {
        float4 xrv[4], wv4[4];
#pragma unroll
        for (int r = 0; r < 4; ++r)
            xrv[r] = *(const float4*)&xs[(rbase + r) * (K + 4) + k];
#pragma unroll
        for (int j = 0; j < 4; ++j)
            wv4[j] = *(const float4*)&wl[(k + j) * 68 + cbase];
#pragma unroll
        for (int r = 0; r < 4; ++r) {
            const float* xp = (const float*)&xrv[r];
#pragma unroll
            for (int j = 0; j < 4; ++j) {
                float xv = xp[j];
                acc[r][0] += xv * wv4[j].x;
                acc[r][1] += xv * wv4[j].y;
                acc[r][2] += xv * wv4[j].z;
                acc[r][3] += xv * wv4[j].w;
            }
        }
    }

#pragma unroll
    for (int r = 0; r < 4; ++r) {
        int row = r0 + rbase + r;
        if (row < n) {
            float4 st = {acc[r][0], acc[r][1], acc[r][2], acc[r][3]};
            *(float4*)&out[(size_t)row * 64 + cbase] = st;
        }
    }
}

// ---------------- fused aggregation: one wave per node ----------------
template <int EP>
__global__ __launch_bounds__(256) void k_agg(const float* __restrict__ t,
                                             const float* __restrict__ dinv,
                                             const int* __restrict__ rowptr,
                                             const int* __restrict__ srcs,
                                             const void* __restrict__ bias,
                                             const float* __restrict__ flags,
                                             void* __restrict__ d_out, size_t emb_base,
                                             float* __restrict__ B_ws, int n) {
    bool f32m = flags[0] > 0.5f;
    int wid = (blockIdx.x * 256 + threadIdx.x) >> 6;
    int lane = threadIdx.x & 63;
    if (wid >= n) return;
    float dv = dinv[wid];
    float acc = t[(size_t)wid * 64 + lane] * dv * dv;
    int e0 = rowptr[wid], e1 = rowptr[wid + 1];
    for (int base = e0; base < e1; base += 64) {
        int m = e1 - base; if (m > 64) m = 64;
        int idx = base + lane;
        int s_l = (idx < e1) ? srcs[idx] : 0;
        float dv_l = (idx < e1) ? dinv[s_l] : 0.0f;
        int j = 0;
        for (; j + 4 <= m; j += 4) {
            int s0 = __shfl(s_l, j, 64),     s1 = __shfl(s_l, j + 1, 64);
            int s2 = __shfl(s_l, j + 2, 64), s3 = __shfl(s_l, j + 3, 64);
            float a0 = __shfl(dv_l, j, 64),     a1 = __shfl(dv_l, j + 1, 64);
            float a2 = __shfl(dv_l, j + 2, 64), a3 = __shfl(dv_l, j + 3, 64);
            float v0 = t[(size_t)s0 * 64 + lane];
            float v1 = t[(size_t)s1 * 64 + lane];
            float v2 = t[(size_t)s2 * 64 + lane];
            float v3 = t[(size_t)s3 * 64 + lane];
            acc += v0 * (a0 * dv);
            acc += v1 * (a1 * dv);
            acc += v2 * (a2 * dv);
            acc += v3 * (a3 * dv);
        }
        for (; j < m; ++j) {
            int s = __shfl(s_l, j, 64);
            float w = __shfl(dv_l, j, 64) * dv;
            acc += t[(size_t)s * 64 + lane] * w;
        }
    }
    acc += loadf(bias, lane, f32m);
    size_t oi = (size_t)wid * 64 + lane;
    if (EP == 0) acc = fmaxf(acc, 0.0f);
    if (f32m) {
        ((float*)d_out)[emb_base + oi] = acc;
    } else {
        B_ws[oi] = acc;
        if (EP == 1) ((bf16*)d_out)[emb_base + oi] = __float2bfloat16(acc);
    }
}

// ---------------- classifier + softmax + argmax: one wave per node ----------------
__global__ __launch_bounds__(256) void k_classifier(const float* __restrict__ flags,
                                                    const void* __restrict__ Wc,
                                                    const void* __restrict__ bc,
                                                    void* __restrict__ out,
                                                    size_t emb_base, size_t soft_base,
                                                    size_t hard_base,
                                                    const float* __restrict__ B_ws,
                                                    int n) {
    __shared__ float wc[40 * 65];
    __shared__ float bcs[40];
    __shared__ float ebuf[4][64];
    bool f32m = flags[0] > 0.5f;
    const float* emb = f32m ? ((const float*)out + emb_base) : B_ws;
    int tid = threadIdx.x;
    for (int i = tid; i < 64 * 40; i += 256) {
        int k = i / 40, c = i % 40;
        wc[c * 65 + k] = loadf(Wc, i, f32m);
    }
    if (tid < 40) bcs[tid] = loadf(bc, tid, f32m);
    int w = tid >> 6, lane = tid & 63;
    int node = blockIdx.x * 4 + w;
    ebuf[w][lane] = (node < n) ? emb[(size_t)node * 64 + lane] : 0.0f;
    __syncthreads();
    if (node >= n) return;

    int c = lane;
    float acc = -INFINITY;
    if (c < 40) {
        acc = bcs[c];
        const float* wp = &wc[c * 65];
#pragma unroll
        for (int k = 0; k < 64; ++k) acc += ebuf[w][k] * wp[k];
        storef(out, (size_t)node * 40 + c, acc, f32m);
    }
    float m = acc;
#pragma unroll
    for (int off = 32; off > 0; off >>= 1) m = fmaxf(m, __shfl_xor(m, off, 64));
    float ex = (c < 40) ? expf(acc - m) : 0.0f;
    float s = ex;
#pragma unroll
    for (int off = 32; off > 0; off >>= 1) s += __shfl_xor(s, off, 64);
    if (c < 40) storef(out, soft_base + (size_t)node * 40 + c, ex / s, f32m);
    float bv = acc;
    int bi = (c < 40) ? c : 1000;
#pragma unroll
    for (int off = 32; off > 0; off >>= 1) {
        float ov = __shfl_xor(bv, off, 64);
        int oi = __shfl_xor(bi, off, 64);
        if (ov > bv || (ov == bv && oi < bi)) { bv = ov; bi = oi; }
    }
    if (lane == 0) storef(out, hard_base + node, (float)bi, f32m);
}

extern "C" void kernel_launch(void* const* d_in, const int* in_sizes, int n_in,
                              void* d_out, int out_size, void* d_ws, size_t ws_size,
                              hipStream_t stream) {
    const void* x  = d_in[0];
    const int*  ei = (const int*)d_in[1];
    const void* W1 = d_in[2];
    const void* b1 = d_in[3];
    const void* W2 = d_in[4];
    const void* b2 = d_in[5];
    const void* Wc = d_in[6];
    const void* bc = d_in[7];

    const int n = in_sizes[0] / 128;   // 100000
    const int E = in_sizes[1] / 2;     // 1200000

    float* ws    = (float*)d_ws;
    const size_t npad = (((size_t)n + 1023) / 1024) * 1024;
    const size_t Epad = (((size_t)E + 255) / 256) * 256;
    float* flags = ws;                          // [0..256); bsum at [128..)
    int*   bsum  = (int*)(ws + 128);
    int*   cnt   = (int*)(ws + 256);            // npad (becomes cursor)
    int*   rowptr= cnt + npad;                  // npad (n+1 used)
    float* dinv  = (float*)(rowptr + npad);     // npad
    int*   srcs  = (int*)(dinv + npad);         // Epad
    float* A     = (float*)(srcs + Epad);       // n*64 f32 (gemm outputs)
    float* B_ws  = A + (size_t)n * 64;          // n*64 f32 (only if !f32m)

    const size_t emb_base  = (size_t)n * 40;
    const size_t soft_base = (size_t)n * 104;
    const size_t hard_base = (size_t)n * 144;
    float* h1_f32m = (float*)d_out + emb_base;  // h1 scratch in emb region (f32m)

    const int gN  = (n + 255) / 256;
    const int gE  = (E + 255) / 256;
    const int nb  = (n + 1023) / 1024;
    const int gG  = (n + 63) / 64;              // 64 rows per gemm block
    const int gW  = (n + 3) / 4;                // one wave per node

    k_detect<<<1, 64, 0, stream>>>(x, ei, flags);

    // CSR build (+ degrees)
    k_zero<<<gN, 256, 0, stream>>>(cnt, n);
    k_hist<<<gE, 256, 0, stream>>>(ei, flags, cnt, E);
    k_block_sums<<<nb, 256, 0, stream>>>(cnt, bsum, n);
    k_scan_bsum<<<1, 256, 0, stream>>>(bsum, nb, rowptr, n, E);
    k_scan_final<<<nb, 256, 0, stream>>>(cnt, bsum, rowptr, cnt, dinv, n);
    k_scatter<<<gE, 256, 0, stream>>>(ei, flags, cnt, srcs, E);

    // conv1: A = x @ W1 ; fused agg + b1 + relu -> h1
    k_gemm3<128, false><<<gG, 256, 0, stream>>>(x, x, W1, flags, A, n);
    k_agg<0><<<gW, 256, 0, stream>>>(A, dinv, rowptr, srcs, b1, flags,
                                     d_out, emb_base, B_ws, n);

    // conv2: A = h1 @ W2 ; fused agg + b2 -> final embedding
    k_gemm3<64, true><<<gG, 256, 0, stream>>>(h1_f32m, B_ws, W2, flags, A, n);
    k_agg<1><<<gW, 256, 0, stream>>>(A, dinv, rowptr, srcs, b2, flags,
                                     d_out, emb_base, B_ws, n);

    // classifier + softmax + argmax
    k_classifier<<<gW, 256, 0, stream>>>(flags, Wc, bc, d_out,
                                         emb_base, soft_base, hard_base, B_ws, n);
}

// Round 6
// 389.783 us; speedup vs baseline: 2.7658x; 1.2718x over previous
//
#include <hip/hip_runtime.h>
#include <hip/hip_bf16.h>
#include <math.h>

typedef __hip_bfloat16 bf16;

// ---------------- dtype-flexible accessors ----------------
__device__ __forceinline__ float loadf(const void* p, size_t i, bool f32m) {
    return f32m ? ((const float*)p)[i]
                : __bfloat162float(((const bf16*)p)[i]);
}
__device__ __forceinline__ void storef(void* p, size_t i, float v, bool f32m) {
    if (f32m) ((float*)p)[i] = v;
    else      ((bf16*)p)[i] = __float2bfloat16(v);
}
// row 0 = src, row 1 = dst; e64 => int64 buffer, read low word
__device__ __forceinline__ int ldidx(const int* w, size_t e, bool e64, size_t E, int row) {
    return e64 ? w[2 * (row * E + e)] : w[row * E + e];
}

// ---------------- dtype detection (one wave) ----------------
__global__ void k_detect(const void* x, const int* ei, float* flags) {
    int lane = threadIdx.x;
    const unsigned short* hx = (const unsigned short*)x;
    unsigned short u = hx[2 * lane];
    int ex = (u >> 7) & 0xFF;
    bool tame = (ex >= 117 && ex <= 136);
    unsigned long long mt = __ballot(tame);
    unsigned long long mz = __ballot(ei[2 * lane + 1] != 0);
    if (lane == 0) {
        flags[0] = (__popcll(mt) >= 48) ? 0.0f : 1.0f;  // 1 => f32 inputs
        flags[1] = (mz == 0ULL) ? 1.0f : 0.0f;          // 1 => int64 edge_index
    }
}

// ---------------- CSR build: 2-level counting sort ----------------
// bucket = dst >> 8 (256 nodes per bucket), NB = ceil(n/256) <= 512

__global__ void k_zero_small(int* __restrict__ p, int m) {
    int i = blockIdx.x * 256 + threadIdx.x;
    if (i < m) p[i] = 0;
}

#define SCB_EPT 16   // edges per thread in hist/scatter (4096 per block)

__global__ __launch_bounds__(256) void k_bucket_hist(const int* __restrict__ ei,
                                                     const float* __restrict__ flags,
                                                     int* __restrict__ bcnt, int E, int NB) {
    __shared__ int lcnt[512];
    bool e64 = flags[1] > 0.5f;
    int tid = threadIdx.x;
    for (int i = tid; i < NB; i += 256) lcnt[i] = 0;
    __syncthreads();
    int base = blockIdx.x * 256 * SCB_EPT;
#pragma unroll
    for (int j = 0; j < SCB_EPT; ++j) {
        int e = base + j * 256 + tid;
        if (e < E) atomicAdd(&lcnt[ldidx(ei, e, e64, E, 1) >> 8], 1);
    }
    __syncthreads();
    for (int i = tid; i < NB; i += 256) {
        int c = lcnt[i];
        if (c) atomicAdd(&bcnt[i], c);
    }
}

// single block of 512: scan bcnt -> bbase (exclusive, NB+1), bcur copy
__global__ __launch_bounds__(512) void k_scan_buckets(const int* __restrict__ bcnt,
                                                      int* __restrict__ bbase,
                                                      int* __restrict__ bcur, int NB) {
    __shared__ int sh[512];
    int tid = threadIdx.x;
    int v = (tid < NB) ? bcnt[tid] : 0;
    sh[tid] = v;
    __syncthreads();
    for (int off = 1; off < 512; off <<= 1) {
        int t = (tid >= off) ? sh[tid - off] : 0;
        __syncthreads();
        sh[tid] += t;
        __syncthreads();
    }
    if (tid < NB) {
        int ex = sh[tid] - v;
        bbase[tid] = ex;
        bcur[tid] = ex;
    }
    if (tid == 0) bbase[NB] = sh[511];
}

// scatter (src,dst) records into bucket regions; per-block LDS rank ->
// consecutive positions per (block,bucket) -> near-sequential writes
__global__ __launch_bounds__(256) void k_bucket_scatter(const int* __restrict__ ei,
                                                        const float* __restrict__ flags,
                                                        int* __restrict__ bcur,
                                                        int2* __restrict__ recs,
                                                        int E, int NB) {
    __shared__ int lcnt[512], lrank[512], lbase[512];
    bool e64 = flags[1] > 0.5f;
    int tid = threadIdx.x;
    for (int i = tid; i < NB; i += 256) { lcnt[i] = 0; lrank[i] = 0; }
    __syncthreads();
    int base = blockIdx.x * 256 * SCB_EPT;
    int s[SCB_EPT], d[SCB_EPT];
#pragma unroll
    for (int j = 0; j < SCB_EPT; ++j) {
        int e = base + j * 256 + tid;
        if (e < E) {
            s[j] = ldidx(ei, e, e64, E, 0);
            d[j] = ldidx(ei, e, e64, E, 1);
            atomicAdd(&lcnt[d[j] >> 8], 1);
        } else d[j] = -1;
    }
    __syncthreads();
    for (int i = tid; i < NB; i += 256) {
        int c = lcnt[i];
        lbase[i] = c ? atomicAdd(&bcur[i], c) : 0;
    }
    __syncthreads();
#pragma unroll
    for (int j = 0; j < SCB_EPT; ++j) {
        if (d[j] >= 0) {
            int b = d[j] >> 8;
            int r = atomicAdd(&lrank[b], 1);
            recs[lbase[b] + r] = make_int2(s[j], d[j]);
        }
    }
}

// one block per bucket: node counts + scan -> rowptr, dinv; then scatter srcs
// into the bucket's contiguous range (L2-local full-line writes)
__global__ __launch_bounds__(256) void k_bucket_csr(const int2* __restrict__ recs,
                                                    const int* __restrict__ bbase,
                                                    int* __restrict__ rowptr,
                                                    float* __restrict__ dinv,
                                                    int* __restrict__ srcs,
                                                    int n, int E) {
    __shared__ int lcnt[256];
    __shared__ int lcur[256];
    int b = blockIdx.x, tid = threadIdx.x;
    int e0 = bbase[b], e1 = bbase[b + 1];
    lcnt[tid] = 0;
    __syncthreads();
    for (int i = e0 + tid; i < e1; i += 256)
        atomicAdd(&lcnt[recs[i].y & 255], 1);
    __syncthreads();
    int c = lcnt[tid];
    lcur[tid] = c;
    __syncthreads();
    for (int off = 1; off < 256; off <<= 1) {
        int t = (tid >= off) ? lcur[tid - off] : 0;
        __syncthreads();
        lcur[tid] += t;
        __syncthreads();
    }
    int rp = bbase[b] + lcur[tid] - c;   // exclusive
    int node = (b << 8) + tid;
    if (node < n) {
        rowptr[node] = rp;
        dinv[node] = rsqrtf((float)(c + 1));
    }
    lcur[tid] = rp;
    __syncthreads();
    for (int i = e0 + tid; i < e1; i += 256) {
        int2 r = recs[i];
        int pos = atomicAdd(&lcur[r.y & 255], 1);
        srcs[pos] = r.x;
    }
    if (b == 0 && tid == 0) rowptr[n] = E;
}

// ---------------- dense transform: out[N,64] = (X[N,K] @ W[K,64]) * rowscale ----------------
// 64 rows/block, X tile + W fully in LDS, 4x4 register tile per thread.
template <int K, bool XF32>
__global__ __launch_bounds__(256) void k_gemm3(const void* __restrict__ Xa,
                                               const void* __restrict__ Xb,
                                               const void* __restrict__ W,
                                               const float* __restrict__ flags,
                                               const float* __restrict__ rowscale,
                                               float* __restrict__ out, int n) {
    __shared__ float xs[64 * (K + 4)];
    __shared__ float wl[K * 68];
    bool f32m = flags[0] > 0.5f;
    const void* X = f32m ? Xa : Xb;
    bool xf32 = XF32 || f32m;
    int tid = threadIdx.x;
    int r0 = blockIdx.x * 64;

    if (f32m) {
        for (int i = tid * 4; i < K * 64; i += 1024) {
            int k = i >> 6, cc = i & 63;
            float4 v = *(const float4*)((const float*)W + i);
            *(float4*)&wl[k * 68 + cc] = v;
        }
    } else {
        for (int i = tid; i < K * 64; i += 256) {
            int k = i >> 6, cc = i & 63;
            wl[k * 68 + cc] = __bfloat162float(((const bf16*)W)[i]);
        }
    }
    if (xf32) {
        for (int i = tid * 4; i < 64 * K; i += 1024) {
            int row = i / K, k = i % K;
            float4 v = {0, 0, 0, 0};
            if (r0 + row < n) v = *(const float4*)((const float*)X + (size_t)(r0 + row) * K + k);
            *(float4*)&xs[row * (K + 4) + k] = v;
        }
    } else {
        for (int i = tid * 4; i < 64 * K; i += 1024) {
            int row = i / K, k = i % K;
            float4 v = {0, 0, 0, 0};
            if (r0 + row < n) {
                const bf16* p = (const bf16*)X + (size_t)(r0 + row) * K + k;
                v.x = __bfloat162float(p[0]); v.y = __bfloat162float(p[1]);
                v.z = __bfloat162float(p[2]); v.w = __bfloat162float(p[3]);
            }
            *(float4*)&xs[row * (K + 4) + k] = v;
        }
    }
    __syncthreads();

    int lane = tid & 63, wv = tid >> 6;
    int rg = lane >> 4, cg = lane & 15;
    int rbase = wv * 16 + rg * 4;
    int cbase = cg * 4;

    float acc[4][4];
#pragma unroll
    for (int r = 0; r < 4; ++r)
#pragma unroll
        for (int c = 0; c < 4; ++c) acc[r][c] = 0.0f;

#pragma unroll 2
    for (int k = 0; k < K; k += 4) {
        float4 xrv[4], wv4[4];
#pragma unroll
        for (int r = 0; r < 4; ++r)
            xrv[r] = *(const float4*)&xs[(rbase + r) * (K + 4) + k];
#pragma unroll
        for (int j = 0; j < 4; ++j)
            wv4[j] = *(const float4*)&wl[(k + j) * 68 + cbase];
#pragma unroll
        for (int r = 0; r < 4; ++r) {
            const float* xp = (const float*)&xrv[r];
#pragma unroll
            for (int j = 0; j < 4; ++j) {
                float xv = xp[j];
                acc[r][0] += xv * wv4[j].x;
                acc[r][1] += xv * wv4[j].y;
                acc[r][2] += xv * wv4[j].z;
                acc[r][3] += xv * wv4[j].w;
            }
        }
    }

#pragma unroll
    for (int r = 0; r < 4; ++r) {
        int row = r0 + rbase + r;
        if (row < n) {
            float sc = rowscale[row];
            float4 st = {acc[r][0] * sc, acc[r][1] * sc, acc[r][2] * sc, acc[r][3] * sc};
            *(float4*)&out[(size_t)row * 64 + cbase] = st;
        }
    }
}

// ---------------- fused aggregation: one wave per node ----------------
// t = A_scaled (rows pre-multiplied by dinv[src]); result = dv*(t[v] + sum t[s]) + bias
template <int EP>
__global__ __launch_bounds__(256) void k_agg(const float* __restrict__ t,
                                             const float* __restrict__ dinv,
                                             const int* __restrict__ rowptr,
                                             const int* __restrict__ srcs,
                                             const void* __restrict__ bias,
                                             const float* __restrict__ flags,
                                             void* __restrict__ d_out, size_t emb_base,
                                             float* __restrict__ B_ws, int n) {
    bool f32m = flags[0] > 0.5f;
    int wid = (blockIdx.x * 256 + threadIdx.x) >> 6;
    int lane = threadIdx.x & 63;
    if (wid >= n) return;
    float dv = dinv[wid];
    float acc = t[(size_t)wid * 64 + lane];
    int e0 = rowptr[wid], e1 = rowptr[wid + 1];
    for (int base = e0; base < e1; base += 64) {
        int m = e1 - base; if (m > 64) m = 64;
        int idx = base + lane;
        int s_l = (idx < e1) ? srcs[idx] : 0;
        int j = 0;
        for (; j + 8 <= m; j += 8) {
            int s0 = __shfl(s_l, j + 0, 64), s1 = __shfl(s_l, j + 1, 64);
            int s2 = __shfl(s_l, j + 2, 64), s3 = __shfl(s_l, j + 3, 64);
            int s4 = __shfl(s_l, j + 4, 64), s5 = __shfl(s_l, j + 5, 64);
            int s6 = __shfl(s_l, j + 6, 64), s7 = __shfl(s_l, j + 7, 64);
            float v0 = t[(size_t)s0 * 64 + lane];
            float v1 = t[(size_t)s1 * 64 + lane];
            float v2 = t[(size_t)s2 * 64 + lane];
            float v3 = t[(size_t)s3 * 64 + lane];
            float v4 = t[(size_t)s4 * 64 + lane];
            float v5 = t[(size_t)s5 * 64 + lane];
            float v6 = t[(size_t)s6 * 64 + lane];
            float v7 = t[(size_t)s7 * 64 + lane];
            acc += ((v0 + v1) + (v2 + v3)) + ((v4 + v5) + (v6 + v7));
        }
        for (; j < m; ++j) {
            int s = __shfl(s_l, j, 64);
            acc += t[(size_t)s * 64 + lane];
        }
    }
    acc = acc * dv + loadf(bias, lane, f32m);
    size_t oi = (size_t)wid * 64 + lane;
    if (EP == 0) acc = fmaxf(acc, 0.0f);
    if (f32m) {
        ((float*)d_out)[emb_base + oi] = acc;
    } else {
        B_ws[oi] = acc;
        if (EP == 1) ((bf16*)d_out)[emb_base + oi] = __float2bfloat16(acc);
    }
}

// ---------------- classifier: 32 nodes/block (8 iters of 4 waves) ----------------
__global__ __launch_bounds__(256) void k_classifier(const float* __restrict__ flags,
                                                    const void* __restrict__ Wc,
                                                    const void* __restrict__ bc,
                                                    void* __restrict__ out,
                                                    size_t emb_base, size_t soft_base,
                                                    size_t hard_base,
                                                    const float* __restrict__ B_ws,
                                                    int n) {
    __shared__ float wc[40 * 65];
    __shared__ float bcs[40];
    __shared__ float ebuf[4][64];
    bool f32m = flags[0] > 0.5f;
    const float* emb = f32m ? ((const float*)out + emb_base) : B_ws;
    int tid = threadIdx.x;
    for (int i = tid; i < 64 * 40; i += 256) {
        int k = i / 40, cc = i % 40;
        wc[cc * 65 + k] = loadf(Wc, i, f32m);
    }
    if (tid < 40) bcs[tid] = loadf(bc, tid, f32m);
    __syncthreads();
    int w = tid >> 6, lane = tid & 63;

    for (int it = 0; it < 8; ++it) {
        int node = blockIdx.x * 32 + it * 4 + w;
        if (node >= n) continue;
        ebuf[w][lane] = emb[(size_t)node * 64 + lane];   // same-wave LDS, no barrier
        int c = lane;
        float acc = -INFINITY;
        if (c < 40) {
            acc = bcs[c];
            const float* wp = &wc[c * 65];
#pragma unroll
            for (int k = 0; k < 64; ++k) acc += ebuf[w][k] * wp[k];
            storef(out, (size_t)node * 40 + c, acc, f32m);
        }
        float m = acc;
#pragma unroll
        for (int off = 32; off > 0; off >>= 1) m = fmaxf(m, __shfl_xor(m, off, 64));
        float ex = (c < 40) ? expf(acc - m) : 0.0f;
        float s = ex;
#pragma unroll
        for (int off = 32; off > 0; off >>= 1) s += __shfl_xor(s, off, 64);
        if (c < 40) storef(out, soft_base + (size_t)node * 40 + c, ex / s, f32m);
        float bv = acc;
        int bi = (c < 40) ? c : 1000;
#pragma unroll
        for (int off = 32; off > 0; off >>= 1) {
            float ov = __shfl_xor(bv, off, 64);
            int oi = __shfl_xor(bi, off, 64);
            if (ov > bv || (ov == bv && oi < bi)) { bv = ov; bi = oi; }
        }
        if (lane == 0) storef(out, hard_base + node, (float)bi, f32m);
    }
}

extern "C" void kernel_launch(void* const* d_in, const int* in_sizes, int n_in,
                              void* d_out, int out_size, void* d_ws, size_t ws_size,
                              hipStream_t stream) {
    const void* x  = d_in[0];
    const int*  ei = (const int*)d_in[1];
    const void* W1 = d_in[2];
    const void* b1 = d_in[3];
    const void* W2 = d_in[4];
    const void* b2 = d_in[5];
    const void* Wc = d_in[6];
    const void* bc = d_in[7];

    const int n = in_sizes[0] / 128;   // 100000
    const int E = in_sizes[1] / 2;     // 1200000
    const int NB = (n + 255) / 256;    // 391 buckets (<= 512)

    float* ws    = (float*)d_ws;
    const size_t npad = (((size_t)n + 1023) / 1024) * 1024;
    const size_t Epad = (((size_t)E + 255) / 256) * 256;
    float* flags  = ws;                         // 256
    int*   bcnt   = (int*)(ws + 256);           // 512
    int*   bbase  = (int*)(ws + 768);           // 768 (NB+1 used)
    int*   bcur   = (int*)(ws + 1536);          // 512
    int*   rowptr = (int*)(ws + 2048);          // npad (n+1 used)
    float* dinv   = (float*)(rowptr + npad);    // npad
    int*   srcs   = (int*)(dinv + npad);        // Epad
    float* A      = (float*)(srcs + Epad);      // n*64 f32 (scaled gemm outputs)
    float* B_ws   = A + (size_t)n * 64;         // n*64 f32 (only if !f32m)
    int2*  recs   = (int2*)B_ws;                // E records, aliases B_ws (dead before use)

    const size_t emb_base  = (size_t)n * 40;
    const size_t soft_base = (size_t)n * 104;
    const size_t hard_base = (size_t)n * 144;
    float* h1_f32m = (float*)d_out + emb_base;  // h1 scratch in emb region (f32m)

    const int gS  = (E + 256 * SCB_EPT - 1) / (256 * SCB_EPT);  // hist/scatter blocks
    const int gG  = (n + 63) / 64;
    const int gW  = (n + 3) / 4;
    const int gC  = (n + 31) / 32;

    k_detect<<<1, 64, 0, stream>>>(x, ei, flags);

    // CSR build via 2-level counting sort
    k_zero_small<<<2, 256, 0, stream>>>(bcnt, 512);
    k_bucket_hist<<<gS, 256, 0, stream>>>(ei, flags, bcnt, E, NB);
    k_scan_buckets<<<1, 512, 0, stream>>>(bcnt, bbase, bcur, NB);
    k_bucket_scatter<<<gS, 256, 0, stream>>>(ei, flags, bcur, recs, E, NB);
    k_bucket_csr<<<NB, 256, 0, stream>>>(recs, bbase, rowptr, dinv, srcs, n, E);

    // conv1: A = (x @ W1)*dinv ; fused agg + b1 + relu -> h1
    k_gemm3<128, false><<<gG, 256, 0, stream>>>(x, x, W1, flags, dinv, A, n);
    k_agg<0><<<gW, 256, 0, stream>>>(A, dinv, rowptr, srcs, b1, flags,
                                     d_out, emb_base, B_ws, n);

    // conv2: A = (h1 @ W2)*dinv ; fused agg + b2 -> final embedding
    k_gemm3<64, true><<<gG, 256, 0, stream>>>(h1_f32m, B_ws, W2, flags, dinv, A, n);
    k_agg<1><<<gW, 256, 0, stream>>>(A, dinv, rowptr, srcs, b2, flags,
                                     d_out, emb_base, B_ws, n);

    // classifier + softmax + argmax
    k_classifier<<<gC, 256, 0, stream>>>(flags, Wc, bc, d_out,
                                         emb_base, soft_base, hard_base, B_ws, n);
}